// Round 9
// baseline (300.497 us; speedup 1.0000x reference)
//
#include <hip/hip_runtime.h>

// GCN autoencoder: N=50000, E=800000, 128 -> 16 -> 128.
// Round 9: fine buckets (782 x 64 nodes, bucket = dst>>6) end-to-end.
//  - k3/k4: 512-thread blocks, 4 KB LDS acc -> ~24 waves/CU resident
//    (R6/R8 used 1024-thread blocks: only ~13 waves resident, 40% occ, 80 us).
//  - 4 lanes/edge with float4 feature gathers: 4x fewer scan instructions
//    than the 16-lane scheme; unroll x4 for MLP.
//  - k1 scatter now writes short runs (~4 edges) -> accept bounded write
//    amplification; guarded by R4 evidence (52 MB was 55 us; expect ~20 MB).

#define N_NODES  50000
#define N_EDGES  800000
#define D_IN     128
#define D_H      16
#define K_FINE   782     // buckets: dst>>6, max 49999>>6 = 781
#define NPF      64      // nodes per bucket
#define FCAP     1280    // slots/bucket; mean 1023, sd 32 -> +8 sigma
#define PA_BLKS  256
#define PA_CHUNK 3125    // 800000/256
#define GC_PAD   16      // gcur stride in ints (64 B line padding)

// ---- K1: fused [phase A bucket scatter (blocks 0..255)] + [h1 GEMM] ----
__global__ __launch_bounds__(256) void k1_fused(
        const int* __restrict__ src, const int* __restrict__ dst,
        const float* __restrict__ x, const float* __restrict__ W1,
        int* __restrict__ gcur, float* __restrict__ h1, int* __restrict__ arr) {
    __shared__ float w1s[D_IN * D_H];   // GEMM segment (8 KB)
    __shared__ int hist[K_FINE];        // phase A segment (3.1+3.1 KB)
    __shared__ int cur[K_FINE];
    int bid = blockIdx.x;
    int tid = threadIdx.x;

    if (bid < PA_BLKS) {
        // ---- phase A: bucket scatter of packed (src<<6 | dst&63) ----
        int e0 = bid * PA_CHUNK;
        for (int b = tid; b < K_FINE; b += 256) hist[b] = 0;
        __syncthreads();
        for (int i = tid; i < PA_CHUNK; i += 256) {
            atomicAdd(&hist[dst[e0 + i] >> 6], 1);
        }
        __syncthreads();
        for (int b = tid; b < K_FINE; b += 256)
            cur[b] = b * FCAP + atomicAdd(&gcur[b * GC_PAD], hist[b]);
        __syncthreads();
        for (int i = tid; i < PA_CHUNK; i += 256) {
            int d = dst[e0 + i];
            int s = src[e0 + i];
            int b = d >> 6;
            int pos = atomicAdd(&cur[b], 1);
            if (pos < (b + 1) * FCAP)            // overflow guard (+8 sigma)
                arr[pos] = (s << 6) | (d & 63);
        }
    } else {
        // ---- h1 = x @ W1 ----
        for (int i = tid; i < D_IN * D_H; i += 256) w1s[i] = W1[i];
        __syncthreads();
        int idx = (bid - PA_BLKS) * 256 + tid;   // < 800000 exactly
        int row = idx >> 4;
        int col = idx & 15;
        const float4* xr = (const float4*)(x + row * D_IN);
        float acc = 0.0f;
        #pragma unroll
        for (int k4 = 0; k4 < D_IN / 4; ++k4) {
            float4 v = xr[k4];
            acc += v.x * w1s[(k4 * 4 + 0) * D_H + col];
            acc += v.y * w1s[(k4 * 4 + 1) * D_H + col];
            acc += v.z * w1s[(k4 * 4 + 2) * D_H + col];
            acc += v.w * w1s[(k4 * 4 + 3) * D_H + col];
        }
        h1[idx] = acc;
    }
}

// ---- K2: per-bucket degree -> dinv, scale h1 -> h1s = h1*dinv in place ----
__global__ __launch_bounds__(256) void k2_deg_scale(
        const int* __restrict__ arr, const int* __restrict__ gcur,
        float* __restrict__ h1, float* __restrict__ dinv) {
    __shared__ int cnt[NPF];
    __shared__ float sdi[NPF];
    int k = blockIdx.x, tid = threadIdx.x;
    if (tid < NPF) cnt[tid] = 0;
    __syncthreads();
    int count = min(gcur[k * GC_PAD], FCAP);
    int base = k * FCAP;
    for (int i = tid; i < count; i += 256) atomicAdd(&cnt[arr[base + i] & 63], 1);
    __syncthreads();
    int n0 = k * NPF;
    int ncnt = min(NPF, N_NODES - n0);
    if (tid < ncnt) {
        float di = rsqrtf((float)cnt[tid] + 1.0f);   // +1 = self loop
        sdi[tid] = di;
        dinv[n0 + tid] = di;
    }
    __syncthreads();
    for (int g = tid; g < ncnt * 4; g += 256) {      // float4 groups
        int i = g >> 2;
        float di = sdi[i];
        float4* p = (float4*)(h1 + (n0 + i) * D_H);
        float4 v = p[g & 3];
        v.x *= di; v.y *= di; v.z *= di; v.w *= di;
        p[g & 3] = v;
    }
}

// ---- K3: encoder aggregation: zs[i] = di*( di*(acc + h1s_self) + b1 ) ----
// 4 lanes per edge (float4 gather), unroll x4.
__global__ __launch_bounds__(512) void k3_agg_enc(
        const float* __restrict__ h1s, const int* __restrict__ arr,
        const int* __restrict__ gcur, const float* __restrict__ dinv,
        const float* __restrict__ b1, float* __restrict__ zs) {
    __shared__ __align__(16) float acc[NPF * D_H];   // 4 KB
    int k = blockIdx.x, tid = threadIdx.x;
    for (int i = tid; i < NPF * D_H; i += 512) acc[i] = 0.0f;
    __syncthreads();
    int count = min(gcur[k * GC_PAD], FCAP);
    int base = k * FCAP;
    int q = tid & 3;           // float4 quadrant of the 16-ch row
    {
        int i = tid >> 2;      // i-slot 0..127
        for (; i + 384 < count; i += 512) {
            int p0 = arr[base + i];
            int p1 = arr[base + i + 128];
            int p2 = arr[base + i + 256];
            int p3 = arr[base + i + 384];
            float4 v0 = ((const float4*)(h1s + (p0 >> 6) * D_H))[q];
            float4 v1 = ((const float4*)(h1s + (p1 >> 6) * D_H))[q];
            float4 v2 = ((const float4*)(h1s + (p2 >> 6) * D_H))[q];
            float4 v3 = ((const float4*)(h1s + (p3 >> 6) * D_H))[q];
            int l0 = (p0 & 63) * D_H + q * 4;
            int l1 = (p1 & 63) * D_H + q * 4;
            int l2 = (p2 & 63) * D_H + q * 4;
            int l3 = (p3 & 63) * D_H + q * 4;
            atomicAdd(&acc[l0], v0.x); atomicAdd(&acc[l0+1], v0.y); atomicAdd(&acc[l0+2], v0.z); atomicAdd(&acc[l0+3], v0.w);
            atomicAdd(&acc[l1], v1.x); atomicAdd(&acc[l1+1], v1.y); atomicAdd(&acc[l1+2], v1.z); atomicAdd(&acc[l1+3], v1.w);
            atomicAdd(&acc[l2], v2.x); atomicAdd(&acc[l2+1], v2.y); atomicAdd(&acc[l2+2], v2.z); atomicAdd(&acc[l2+3], v2.w);
            atomicAdd(&acc[l3], v3.x); atomicAdd(&acc[l3+1], v3.y); atomicAdd(&acc[l3+2], v3.z); atomicAdd(&acc[l3+3], v3.w);
        }
        for (; i < count; i += 128) {
            int p = arr[base + i];
            float4 v = ((const float4*)(h1s + (p >> 6) * D_H))[q];
            int l = (p & 63) * D_H + q * 4;
            atomicAdd(&acc[l], v.x); atomicAdd(&acc[l+1], v.y); atomicAdd(&acc[l+2], v.z); atomicAdd(&acc[l+3], v.w);
        }
    }
    __syncthreads();
    int n0 = k * NPF;
    int ncnt = min(NPF, N_NODES - n0);
    for (int idx = tid; idx < ncnt * D_H; idx += 512) {
        int i = n0 + (idx >> 4);
        int c = idx & 15;
        float di = dinv[i];
        zs[i * D_H + c] = di * (di * (acc[idx] + h1s[i * D_H + c]) + b1[c]);
    }
}

// ---- K4: decoder aggregation + W2 GEMM + b2 fused; writes out directly ----
__global__ __launch_bounds__(512) void k4_agg_dec_out(
        const float* __restrict__ zs, const int* __restrict__ arr,
        const int* __restrict__ gcur, const float* __restrict__ dinv,
        const float* __restrict__ W2, const float* __restrict__ b2,
        float* __restrict__ out) {
    __shared__ __align__(16) float acc[NPF * D_H];   // 4 KB
    __shared__ __align__(16) float w2s[D_H * D_IN];  // 8 KB
    int k = blockIdx.x, tid = threadIdx.x;
    for (int i = tid; i < NPF * D_H; i += 512) acc[i] = 0.0f;
    for (int i = tid; i < D_H * D_IN; i += 512) w2s[i] = W2[i];
    __syncthreads();
    int count = min(gcur[k * GC_PAD], FCAP);
    int base = k * FCAP;
    int q = tid & 3;
    {
        int i = tid >> 2;
        for (; i + 384 < count; i += 512) {
            int p0 = arr[base + i];
            int p1 = arr[base + i + 128];
            int p2 = arr[base + i + 256];
            int p3 = arr[base + i + 384];
            float4 v0 = ((const float4*)(zs + (p0 >> 6) * D_H))[q];
            float4 v1 = ((const float4*)(zs + (p1 >> 6) * D_H))[q];
            float4 v2 = ((const float4*)(zs + (p2 >> 6) * D_H))[q];
            float4 v3 = ((const float4*)(zs + (p3 >> 6) * D_H))[q];
            int l0 = (p0 & 63) * D_H + q * 4;
            int l1 = (p1 & 63) * D_H + q * 4;
            int l2 = (p2 & 63) * D_H + q * 4;
            int l3 = (p3 & 63) * D_H + q * 4;
            atomicAdd(&acc[l0], v0.x); atomicAdd(&acc[l0+1], v0.y); atomicAdd(&acc[l0+2], v0.z); atomicAdd(&acc[l0+3], v0.w);
            atomicAdd(&acc[l1], v1.x); atomicAdd(&acc[l1+1], v1.y); atomicAdd(&acc[l1+2], v1.z); atomicAdd(&acc[l1+3], v1.w);
            atomicAdd(&acc[l2], v2.x); atomicAdd(&acc[l2+1], v2.y); atomicAdd(&acc[l2+2], v2.z); atomicAdd(&acc[l2+3], v2.w);
            atomicAdd(&acc[l3], v3.x); atomicAdd(&acc[l3+1], v3.y); atomicAdd(&acc[l3+2], v3.z); atomicAdd(&acc[l3+3], v3.w);
        }
        for (; i < count; i += 128) {
            int p = arr[base + i];
            float4 v = ((const float4*)(zs + (p >> 6) * D_H))[q];
            int l = (p & 63) * D_H + q * 4;
            atomicAdd(&acc[l], v.x); atomicAdd(&acc[l+1], v.y); atomicAdd(&acc[l+2], v.z); atomicAdd(&acc[l+3], v.w);
        }
    }
    __syncthreads();
    int n0 = k * NPF;
    int ncnt = min(NPF, N_NODES - n0);
    // agg2 in place: acc = di*(acc + zs_self)
    for (int idx = tid; idx < ncnt * D_H; idx += 512) {
        int i = n0 + (idx >> 4);
        float di = dinv[i];
        acc[idx] = di * (acc[idx] + zs[i * D_H + (idx & 15)]);
    }
    __syncthreads();
    // out[n][j4] = b2[j4] + sum_c acc[n][c]*W2[c][j4]  (float4 over j)
    const float4* w2s4 = (const float4*)w2s;
    const float4* b2_4 = (const float4*)b2;
    for (int g = tid; g < ncnt * (D_IN / 4); g += 512) {
        int n = g >> 5;
        int j4 = g & 31;
        const float* a = &acc[n * D_H];
        float4 v = b2_4[j4];
        #pragma unroll
        for (int c = 0; c < D_H; ++c) {
            float ac = a[c];
            float4 w = w2s4[c * (D_IN / 4) + j4];
            v.x += ac * w.x; v.y += ac * w.y; v.z += ac * w.z; v.w += ac * w.w;
        }
        ((float4*)(out + (n0 + n) * D_IN))[j4] = v;
    }
}

extern "C" void kernel_launch(void* const* d_in, const int* in_sizes, int n_in,
                              void* d_out, int out_size, void* d_ws, size_t ws_size,
                              hipStream_t stream) {
    const float* x  = (const float*)d_in[0];
    const int*   ei = (const int*)d_in[1];   // [2, E]: src then dst
    const float* W1 = (const float*)d_in[2];
    const float* b1 = (const float*)d_in[3];
    const float* W2 = (const float*)d_in[4];
    const float* b2 = (const float*)d_in[5];
    float* out = (float*)d_out;

    const int* src = ei;
    const int* dst = ei + N_EDGES;

    // ws carve: gcur[782*16] | dinv[N] | h1[N*16] | zs[N*16] | arr[782*1280]  (~10.8 MB)
    char* base = (char*)d_ws;
    int*   gcur = (int*)base;                  base += K_FINE * GC_PAD * 4;
    float* dinv = (float*)base;                base += N_NODES * 4;
    float* h1   = (float*)base;                base += N_NODES * D_H * 4;
    float* zs   = (float*)base;                base += N_NODES * D_H * 4;
    int*   arr  = (int*)base;                  base += K_FINE * FCAP * 4;

    hipMemsetAsync(gcur, 0, K_FINE * GC_PAD * sizeof(int), stream);

    k1_fused<<<PA_BLKS + (N_NODES * D_H / 256), 256, 0, stream>>>(src, dst, x, W1, gcur, h1, arr);
    k2_deg_scale<<<K_FINE, 256, 0, stream>>>(arr, gcur, h1, dinv);
    k3_agg_enc<<<K_FINE, 512, 0, stream>>>(h1, arr, gcur, dinv, b1, zs);
    k4_agg_dec_out<<<K_FINE, 512, 0, stream>>>(zs, arr, gcur, dinv, W2, b2, out);
}

// Round 10
// 268.804 us; speedup vs baseline: 1.1179x; 1.1179x over previous
//
#include <hip/hip_runtime.h>

// GCN autoencoder: N=50000, E=800000, 128 -> 16 -> 128.
// Round 10: R8 geometry (512 buckets x 98 nodes, 16-lane/edge LDS accumulate,
// conflict-free ds_add) + the R9 lesson: the gather loop's arr reads were a
// dependent vmem chain head that serialized every unrolled batch (~1 gather in
// flight per wave across R6/R8/R9 by Little's law). Fix: stage the bucket's
// arr slice into LDS once (coalesced), then the edge loop issues 8 independent
// feature gathers per iteration with no vmem dependency between them.

#define N_NODES  50000
#define N_EDGES  800000
#define D_IN     128
#define D_H      16
#define K_BUCK   512
#define NPB2     98      // nodes per bucket: bucket = dst / 98 (max 49999/98 = 510)
#define BSHIFT   11
#define BCAP     (1 << BSHIFT)   // 2048 slots; mean 1562, sd 40 -> 12 sigma margin
#define PA_BLKS  256
#define PA_CHUNK 3125    // 800000/256
#define GC_PAD   16      // gcur stride in ints (64 B line padding)

// ---- K1: fused [phase A bucket scatter (blocks 0..255)] + [h1 GEMM] ----
__global__ __launch_bounds__(256) void k1_fused(
        const int* __restrict__ src, const int* __restrict__ dst,
        const float* __restrict__ x, const float* __restrict__ W1,
        int* __restrict__ gcur, float* __restrict__ h1, int* __restrict__ arr) {
    __shared__ float w1s[D_IN * D_H];   // GEMM segment (8 KB)
    __shared__ int hist[K_BUCK];        // phase A segment (2+2 KB)
    __shared__ int cur[K_BUCK];
    int bid = blockIdx.x;
    int tid = threadIdx.x;

    if (bid < PA_BLKS) {
        // ---- phase A: bucket scatter of packed (src<<7 | local_dst) ----
        int e0 = bid * PA_CHUNK;
        for (int b = tid; b < K_BUCK; b += 256) hist[b] = 0;
        __syncthreads();
        for (int i = tid; i < PA_CHUNK; i += 256) {
            int d = dst[e0 + i];
            atomicAdd(&hist[d / NPB2], 1);
        }
        __syncthreads();
        for (int b = tid; b < K_BUCK; b += 256)
            cur[b] = (b << BSHIFT) + atomicAdd(&gcur[b * GC_PAD], hist[b]);
        __syncthreads();
        for (int i = tid; i < PA_CHUNK; i += 256) {
            int d = dst[e0 + i];
            int s = src[e0 + i];
            int b = d / NPB2;
            int pos = atomicAdd(&cur[b], 1);
            if (pos < ((b + 1) << BSHIFT))       // overflow guard (12 sigma)
                arr[pos] = (s << 7) | (d - b * NPB2);
        }
    } else {
        // ---- h1 = x @ W1 ----
        for (int i = tid; i < D_IN * D_H; i += 256) w1s[i] = W1[i];
        __syncthreads();
        int idx = (bid - PA_BLKS) * 256 + tid;   // < 800000 exactly
        int row = idx >> 4;
        int col = idx & 15;
        const float4* xr = (const float4*)(x + row * D_IN);
        float acc = 0.0f;
        #pragma unroll
        for (int k4 = 0; k4 < D_IN / 4; ++k4) {
            float4 v = xr[k4];
            acc += v.x * w1s[(k4 * 4 + 0) * D_H + col];
            acc += v.y * w1s[(k4 * 4 + 1) * D_H + col];
            acc += v.z * w1s[(k4 * 4 + 2) * D_H + col];
            acc += v.w * w1s[(k4 * 4 + 3) * D_H + col];
        }
        h1[idx] = acc;
    }
}

// ---- K2: per-bucket degree -> dinv, then scale h1 -> h1s = h1*dinv in place ----
__global__ __launch_bounds__(256) void k2_deg_scale(
        const int* __restrict__ arr, const int* __restrict__ gcur,
        float* __restrict__ h1, float* __restrict__ dinv) {
    __shared__ int cnt[NPB2];
    __shared__ float sdi[NPB2];
    int k = blockIdx.x, tid = threadIdx.x;
    for (int i = tid; i < NPB2; i += 256) cnt[i] = 0;
    __syncthreads();
    int count = min(gcur[k * GC_PAD], BCAP);
    int base = k << BSHIFT;
    for (int i = tid; i < count; i += 256) atomicAdd(&cnt[arr[base + i] & 127], 1);
    __syncthreads();
    int n0 = k * NPB2;
    int ncnt = min(NPB2, N_NODES - n0);
    for (int i = tid; i < ncnt; i += 256) {
        float di = rsqrtf((float)cnt[i] + 1.0f);   // +1 = self loop
        sdi[i] = di;
        dinv[n0 + i] = di;
    }
    __syncthreads();
    for (int g = tid; g < ncnt * 4; g += 256) {    // float4 groups
        int i = g >> 2;
        float di = sdi[i];
        float4* p = (float4*)(h1 + (n0 + i) * D_H);
        float4 v = p[g & 3];
        v.x *= di; v.y *= di; v.z *= di; v.w *= di;
        p[g & 3] = v;
    }
}

// ---- K3: encoder aggregation: zs[i] = di*( di*(acc + h1s_self) + b1 ) ----
// arr slice staged in LDS; 16 lanes/edge; 8 independent gathers in flight.
__global__ __launch_bounds__(512) void k3_agg_enc(
        const float* __restrict__ h1s, const int* __restrict__ arr,
        const int* __restrict__ gcur, const float* __restrict__ dinv,
        const float* __restrict__ b1, float* __restrict__ zs) {
    __shared__ __align__(16) float acc[NPB2 * D_H];   // 6.3 KB
    __shared__ int sarr[BCAP];                        // 8 KB
    int k = blockIdx.x, tid = threadIdx.x;
    int count = min(gcur[k * GC_PAD], BCAP);
    int base = k << BSHIFT;
    for (int i = tid; i < count; i += 512) sarr[i] = arr[base + i];
    for (int i = tid; i < NPB2 * D_H; i += 512) acc[i] = 0.0f;
    __syncthreads();
    int ch = tid & 15;
    int i = tid >> 4;                 // i-slot 0..31, stride 32
    for (; i + 224 < count; i += 256) {
        int p0 = sarr[i];
        int p1 = sarr[i + 32];
        int p2 = sarr[i + 64];
        int p3 = sarr[i + 96];
        int p4 = sarr[i + 128];
        int p5 = sarr[i + 160];
        int p6 = sarr[i + 192];
        int p7 = sarr[i + 224];
        float v0 = h1s[(p0 >> 7) * D_H + ch];
        float v1 = h1s[(p1 >> 7) * D_H + ch];
        float v2 = h1s[(p2 >> 7) * D_H + ch];
        float v3 = h1s[(p3 >> 7) * D_H + ch];
        float v4 = h1s[(p4 >> 7) * D_H + ch];
        float v5 = h1s[(p5 >> 7) * D_H + ch];
        float v6 = h1s[(p6 >> 7) * D_H + ch];
        float v7 = h1s[(p7 >> 7) * D_H + ch];
        atomicAdd(&acc[(p0 & 127) * D_H + ch], v0);
        atomicAdd(&acc[(p1 & 127) * D_H + ch], v1);
        atomicAdd(&acc[(p2 & 127) * D_H + ch], v2);
        atomicAdd(&acc[(p3 & 127) * D_H + ch], v3);
        atomicAdd(&acc[(p4 & 127) * D_H + ch], v4);
        atomicAdd(&acc[(p5 & 127) * D_H + ch], v5);
        atomicAdd(&acc[(p6 & 127) * D_H + ch], v6);
        atomicAdd(&acc[(p7 & 127) * D_H + ch], v7);
    }
    for (; i < count; i += 32) {
        int p = sarr[i];
        atomicAdd(&acc[(p & 127) * D_H + ch], h1s[(p >> 7) * D_H + ch]);
    }
    __syncthreads();
    int n0 = k * NPB2;
    int ncnt = min(NPB2, N_NODES - n0);
    for (int idx = tid; idx < ncnt * D_H; idx += 512) {
        int nn = n0 + (idx >> 4);
        int c = idx & 15;
        float di = dinv[nn];
        zs[nn * D_H + c] = di * (di * (acc[idx] + h1s[nn * D_H + c]) + b1[c]);
    }
}

// ---- K4: decoder aggregation + W2 GEMM + b2 fused; writes out directly ----
__global__ __launch_bounds__(512) void k4_agg_dec_out(
        const float* __restrict__ zs, const int* __restrict__ arr,
        const int* __restrict__ gcur, const float* __restrict__ dinv,
        const float* __restrict__ W2, const float* __restrict__ b2,
        float* __restrict__ out) {
    __shared__ __align__(16) float acc[NPB2 * D_H];   // 6.3 KB
    __shared__ __align__(16) float w2s[D_H * D_IN];   // 8 KB
    __shared__ int sarr[BCAP];                        // 8 KB
    int k = blockIdx.x, tid = threadIdx.x;
    int count = min(gcur[k * GC_PAD], BCAP);
    int base = k << BSHIFT;
    for (int i = tid; i < count; i += 512) sarr[i] = arr[base + i];
    for (int i = tid; i < NPB2 * D_H; i += 512) acc[i] = 0.0f;
    for (int i = tid; i < D_H * D_IN; i += 512) w2s[i] = W2[i];
    __syncthreads();
    int ch = tid & 15;
    int i = tid >> 4;                 // i-slot 0..31, stride 32
    for (; i + 224 < count; i += 256) {
        int p0 = sarr[i];
        int p1 = sarr[i + 32];
        int p2 = sarr[i + 64];
        int p3 = sarr[i + 96];
        int p4 = sarr[i + 128];
        int p5 = sarr[i + 160];
        int p6 = sarr[i + 192];
        int p7 = sarr[i + 224];
        float v0 = zs[(p0 >> 7) * D_H + ch];
        float v1 = zs[(p1 >> 7) * D_H + ch];
        float v2 = zs[(p2 >> 7) * D_H + ch];
        float v3 = zs[(p3 >> 7) * D_H + ch];
        float v4 = zs[(p4 >> 7) * D_H + ch];
        float v5 = zs[(p5 >> 7) * D_H + ch];
        float v6 = zs[(p6 >> 7) * D_H + ch];
        float v7 = zs[(p7 >> 7) * D_H + ch];
        atomicAdd(&acc[(p0 & 127) * D_H + ch], v0);
        atomicAdd(&acc[(p1 & 127) * D_H + ch], v1);
        atomicAdd(&acc[(p2 & 127) * D_H + ch], v2);
        atomicAdd(&acc[(p3 & 127) * D_H + ch], v3);
        atomicAdd(&acc[(p4 & 127) * D_H + ch], v4);
        atomicAdd(&acc[(p5 & 127) * D_H + ch], v5);
        atomicAdd(&acc[(p6 & 127) * D_H + ch], v6);
        atomicAdd(&acc[(p7 & 127) * D_H + ch], v7);
    }
    for (; i < count; i += 32) {
        int p = sarr[i];
        atomicAdd(&acc[(p & 127) * D_H + ch], zs[(p >> 7) * D_H + ch]);
    }
    __syncthreads();
    int n0 = k * NPB2;
    int ncnt = min(NPB2, N_NODES - n0);
    // agg2 in place: acc = di*(acc + zs_self)
    for (int idx = tid; idx < ncnt * D_H; idx += 512) {
        int nn = n0 + (idx >> 4);
        float di = dinv[nn];
        acc[idx] = di * (acc[idx] + zs[nn * D_H + (idx & 15)]);
    }
    __syncthreads();
    // out[n][j4] = b2[j4] + sum_c acc[n][c]*W2[c][j4]  (float4 over j)
    const float4* w2s4 = (const float4*)w2s;
    const float4* b2_4 = (const float4*)b2;
    for (int g = tid; g < ncnt * (D_IN / 4); g += 512) {
        int n = g >> 5;
        int j4 = g & 31;
        const float* a = &acc[n * D_H];
        float4 v = b2_4[j4];
        #pragma unroll
        for (int c = 0; c < D_H; ++c) {
            float ac = a[c];
            float4 w = w2s4[c * (D_IN / 4) + j4];
            v.x += ac * w.x; v.y += ac * w.y; v.z += ac * w.z; v.w += ac * w.w;
        }
        ((float4*)(out + (n0 + n) * D_IN))[j4] = v;
    }
}

extern "C" void kernel_launch(void* const* d_in, const int* in_sizes, int n_in,
                              void* d_out, int out_size, void* d_ws, size_t ws_size,
                              hipStream_t stream) {
    const float* x  = (const float*)d_in[0];
    const int*   ei = (const int*)d_in[1];   // [2, E]: src then dst
    const float* W1 = (const float*)d_in[2];
    const float* b1 = (const float*)d_in[3];
    const float* W2 = (const float*)d_in[4];
    const float* b2 = (const float*)d_in[5];
    float* out = (float*)d_out;

    const int* src = ei;
    const int* dst = ei + N_EDGES;

    // ws carve: gcur[512*16] | dinv[N] | h1[N*16] | zs[N*16] | arr[512*2048]  (~10.8 MB)
    char* base = (char*)d_ws;
    int*   gcur = (int*)base;                  base += K_BUCK * GC_PAD * 4;
    float* dinv = (float*)base;                base += N_NODES * 4;
    float* h1   = (float*)base;                base += N_NODES * D_H * 4;
    float* zs   = (float*)base;                base += N_NODES * D_H * 4;
    int*   arr  = (int*)base;                  base += K_BUCK * BCAP * 4;

    hipMemsetAsync(gcur, 0, K_BUCK * GC_PAD * sizeof(int), stream);

    k1_fused<<<PA_BLKS + (N_NODES * D_H / 256), 256, 0, stream>>>(src, dst, x, W1, gcur, h1, arr);
    k2_deg_scale<<<K_BUCK, 256, 0, stream>>>(arr, gcur, h1, dinv);
    k3_agg_enc<<<K_BUCK, 512, 0, stream>>>(h1, arr, gcur, dinv, b1, zs);
    k4_agg_dec_out<<<K_BUCK, 512, 0, stream>>>(zs, arr, gcur, dinv, W2, b2, out);
}